// Round 4
// baseline (39.915 us; speedup 1.0000x reference)
//
#include <hip/hip_runtime.h>
#include <hip/hip_fp16.h>

// C51 categorical projection — single-wave workgroups, dual f16 tiles.
//
// TPB=64 (one wave per block): no cross-wave barriers, every wave self-paced
// -> the global load/store streams of ~12+ independent waves/CU interleave
// freely instead of stalling in 4-wave barrier lockstep.
// tileA = staged probs (f16), tileB = output bins (f16), 13056 B total.
// Walk: fidx_j = clamp(fma(g, j-25, 2.5r+25), 0, 50) is monotone with step
// g <= 0.99 < 1, so floor advances by <= 1 per atom -> two-register walk with
// write-only LDS emission (no read-modify-write).

#define NUM_ATOMS 51
#define TPB 64

constexpr int TILE_ELEMS = TPB * NUM_ATOMS;          // 3264 halves per tile
constexpr int F4_PER_BLOCK = TILE_ELEMS / 4;         // 816 float4 groups
constexpr int F4_FULL = F4_PER_BLOCK / TPB;          // 12 full iters
constexpr int F4_TAIL = F4_PER_BLOCK - F4_FULL * TPB; // 48 lanes in tail
constexpr int Z16   = (TILE_ELEMS * 2) / 16;         // 408 uint4 to zero
constexpr int Z_FULL = Z16 / TPB;                    // 6
constexpr int Z_TAIL = Z16 - Z_FULL * TPB;           // 24

__global__ __launch_bounds__(TPB) void catproj_kernel(
    const float* __restrict__ reward,
    const float* __restrict__ probs,
    const float* __restrict__ not_done,
    float* __restrict__ out)
{
    __shared__ __align__(16) __half tileA[TILE_ELEMS];  // staged probs
    __shared__ __align__(16) __half tileB[TILE_ELEMS];  // output bins

    const int t = threadIdx.x;                 // lane (single wave)
    const int blockBase = blockIdx.x * TILE_ELEMS;

    // ---- 1a. stage probs -> tileA (f16), coalesced float4 reads ----
    const float4* __restrict__ in4 = reinterpret_cast<const float4*>(probs + blockBase);
    #pragma unroll
    for (int i = 0; i < F4_FULL; ++i) {
        const int idx = i * TPB + t;
        const float4 v = in4[idx];
        __half2 lo = __floats2half2_rn(v.x, v.y);
        __half2 hi = __floats2half2_rn(v.z, v.w);
        uint2 u;
        u.x = *reinterpret_cast<const unsigned int*>(&lo);
        u.y = *reinterpret_cast<const unsigned int*>(&hi);
        *reinterpret_cast<uint2*>(&tileA[4 * idx]) = u;
    }
    if (t < F4_TAIL) {
        const int idx = F4_FULL * TPB + t;
        const float4 v = in4[idx];
        __half2 lo = __floats2half2_rn(v.x, v.y);
        __half2 hi = __floats2half2_rn(v.z, v.w);
        uint2 u;
        u.x = *reinterpret_cast<const unsigned int*>(&lo);
        u.y = *reinterpret_cast<const unsigned int*>(&hi);
        *reinterpret_cast<uint2*>(&tileA[4 * idx]) = u;
    }

    // ---- 1b. zero tileB (fused into staging phase, same barrier) ----
    {
        uint4* z4 = reinterpret_cast<uint4*>(tileB);
        const uint4 z = make_uint4(0, 0, 0, 0);
        #pragma unroll
        for (int i = 0; i < Z_FULL; ++i) z4[i * TPB + t] = z;
        if (t < Z_TAIL) z4[Z_FULL * TPB + t] = z;
    }
    __syncthreads();   // single wave: compiles to waitcnt (+cheap s_barrier)

    // ---- 2. monotone register walk: read tileA, write-only tileB ----
    const int b = blockIdx.x * TPB + t;
    const float r = reward[b];
    const float g = 0.99f * not_done[b];         // exactly 0.0 or 1.0 scaled
    const float base = fmaf(2.5f, r, 25.0f);     // 2.5*(r+10) - 25g + 25g...
    // fidx_j = clamp(base + g*(j-25), 0, 50)  ==  (clip(r+g*z_j)+10)*2.5

    const __half* __restrict__ rowA = &tileA[t * NUM_ATOMS];
    __half* __restrict__ rowB = &tileB[t * NUM_ATOMS];

    float cur = 0.0f;   // mass for bin `prev`
    float nxt = 0.0f;   // mass for bin `prev + 1`
    int   prev = -1;

    #pragma unroll
    for (int j = 0; j < NUM_ATOMS; ++j) {
        const float pj = __half2float(rowA[j]);          // ds_read_u16 imm-offset
        float fidx = fmaf(g, (float)(j - 25), base);
        fidx = fminf(fmaxf(fidx, 0.0f), 50.0f);          // v_med3_f32
        const float lf = floorf(fidx);
        const int  li  = (int)lf;

        const bool adv = (li != prev);                   // advance by exactly 1
        cur  = adv ? nxt  : cur;
        nxt  = adv ? 0.0f : nxt;
        prev = li;

        const float uc = fidx - lf;                      // exact
        const float lc = 1.0f - uc;                      // == ceil-fidx; same-case: 1
        cur = fmaf(lc, pj, cur);
        nxt = fmaf(uc, pj, nxt);

        rowB[li] = __float2half(cur);                    // write-only, last wins
    }
    {   // epilogue: flush upper neighbor (guard li==50 exact-integral case)
        const bool hasNext = (prev < NUM_ATOMS - 1);
        const int   ua = hasNext ? prev + 1 : prev;
        const float uv = hasNext ? nxt : cur;
        rowB[ua] = __float2half(uv);
    }
    __syncthreads();

    // ---- 3. writeback tileB -> out (f32), coalesced float4 writes ----
    float4* __restrict__ out4 = reinterpret_cast<float4*>(out + blockBase);
    #pragma unroll
    for (int i = 0; i < F4_FULL; ++i) {
        const int idx = i * TPB + t;
        const uint2 u = *reinterpret_cast<const uint2*>(&tileB[4 * idx]);
        const __half2 lo = *reinterpret_cast<const __half2*>(&u.x);
        const __half2 hi = *reinterpret_cast<const __half2*>(&u.y);
        float4 v;
        v.x = __half2float(__low2half(lo));
        v.y = __half2float(__high2half(lo));
        v.z = __half2float(__low2half(hi));
        v.w = __half2float(__high2half(hi));
        out4[idx] = v;
    }
    if (t < F4_TAIL) {
        const int idx = F4_FULL * TPB + t;
        const uint2 u = *reinterpret_cast<const uint2*>(&tileB[4 * idx]);
        const __half2 lo = *reinterpret_cast<const __half2*>(&u.x);
        const __half2 hi = *reinterpret_cast<const __half2*>(&u.y);
        float4 v;
        v.x = __half2float(__low2half(lo));
        v.y = __half2float(__high2half(lo));
        v.z = __half2float(__low2half(hi));
        v.w = __half2float(__high2half(hi));
        out4[idx] = v;
    }
}

extern "C" void kernel_launch(void* const* d_in, const int* in_sizes, int n_in,
                              void* d_out, int out_size, void* d_ws, size_t ws_size,
                              hipStream_t stream) {
    const float* reward   = (const float*)d_in[0];
    const float* probs    = (const float*)d_in[1];
    const float* not_done = (const float*)d_in[2];
    float* out = (float*)d_out;

    const int bs = in_sizes[0];            // 524288
    const int blocks = bs / TPB;           // 8192 single-wave blocks

    hipLaunchKernelGGL(catproj_kernel, dim3(blocks), dim3(TPB), 0, stream,
                       reward, probs, not_done, out);
}

// Round 6
// 37.786 us; speedup vs baseline: 1.0563x; 1.0563x over previous
//
#include <hip/hip_runtime.h>
#include <hip/hip_fp16.h>

// C51 categorical projection — monotone register-walk, f16 LDS tile,
// NON-TEMPORAL output stores (via native ext_vector_type for the builtin).
//
// Established: occupancy 25/27/48% all give ~38-40 us -> memory-system bound.
// Aggregate traffic 218 MB vs 6.29 TB/s copy ceiling = 34.7 us floor.
// Residual theory: output write-allocate evicts probs from the 256 MB L3
// (working set 214 MB), causing the observed 54 MB HBM re-fetch. nt stores
// keep the output stream out of L2/L3 so probs stays resident.

#define NUM_ATOMS 51
#define TPB 256

typedef float floatx4 __attribute__((ext_vector_type(4)));

constexpr int TILE_ELEMS = TPB * NUM_ATOMS;                // 13056 halves = 26112 B
constexpr int VEC_ITERS  = TILE_ELEMS / (4 * TPB);         // 12 float4 iters
constexpr int VEC_FLOATS = VEC_ITERS * 4 * TPB;            // 12288
constexpr int TAIL_ITERS = (TILE_ELEMS - VEC_FLOATS) / TPB; // 3 scalar iters

__global__ __launch_bounds__(TPB) void catproj_kernel(
    const float* __restrict__ reward,
    const float* __restrict__ probs,
    const float* __restrict__ not_done,
    float* __restrict__ out)
{
    __shared__ __align__(16) __half lds_h[TILE_ELEMS];
    const int t = threadIdx.x;
    const int blockBase = blockIdx.x * TILE_ELEMS;

    // ---- 1. coalesced staging: global f32 probs -> f16 LDS (flat) ----
    const floatx4* __restrict__ in4 = reinterpret_cast<const floatx4*>(probs + blockBase);
    #pragma unroll
    for (int i = 0; i < VEC_ITERS; ++i) {
        const int idx = i * TPB + t;
        const floatx4 v = in4[idx];
        __half2 lo = __floats2half2_rn(v.x, v.y);
        __half2 hi = __floats2half2_rn(v.z, v.w);
        uint2 u;
        u.x = *reinterpret_cast<const unsigned int*>(&lo);
        u.y = *reinterpret_cast<const unsigned int*>(&hi);
        *reinterpret_cast<uint2*>(&lds_h[4 * idx]) = u;    // 8B aligned
    }
    #pragma unroll
    for (int i = 0; i < TAIL_ITERS; ++i) {
        const int f = VEC_FLOATS + i * TPB + t;
        lds_h[f] = __float2half(probs[blockBase + f]);
    }
    __syncthreads();

    // ---- 2. own row -> registers, then zero own row (own segment only,
    //         same-address dependence orders it -> NO barrier needed). ----
    const int row = t * NUM_ATOMS;
    float p[NUM_ATOMS];
    #pragma unroll
    for (int j = 0; j < NUM_ATOMS; ++j) p[j] = __half2float(lds_h[row + j]);
    #pragma unroll
    for (int j = 0; j < NUM_ATOMS; ++j) lds_h[row + j] = __half(0.0f);

    // ---- 3. monotone register walk, write-only f16 emission ----
    const int b = blockIdx.x * TPB + t;
    const float r = reward[b];
    const float g = 0.99f * not_done[b];          // exactly 0.0 or 0.99
    const float base = fmaf(2.5f, r, 25.0f);
    // fidx_j = clamp(base + g*(j-25), 0, 50) == (clip(r + g*z_j, -10,10)+10)*2.5

    float cur = 0.0f;   // mass for bin `prev`
    float nxt = 0.0f;   // mass for bin `prev + 1`
    int   prev = -1;

    #pragma unroll
    for (int j = 0; j < NUM_ATOMS; ++j) {
        float fidx = fmaf(g, (float)(j - 25), base);
        fidx = fminf(fmaxf(fidx, 0.0f), 50.0f);   // v_med3_f32
        const float lf = floorf(fidx);
        const int  li  = (int)lf;

        const bool adv = (li != prev);            // advance by exactly 1 (g<1)
        cur  = adv ? nxt  : cur;
        nxt  = adv ? 0.0f : nxt;
        prev = li;

        const float uc = fidx - lf;               // 0 when integral
        const float lc = 1.0f - uc;               // 1 when integral (matches ref)
        cur = fmaf(lc, p[j], cur);
        nxt = fmaf(uc, p[j], nxt);

        lds_h[row + li] = __float2half(cur);      // write-only; last write wins
    }
    {   // epilogue: flush upper neighbor (prev==50 -> fidx was exactly 50, nxt==0)
        const bool hasNext = (prev < NUM_ATOMS - 1);
        const int   ua = hasNext ? prev + 1 : prev;
        const float uv = hasNext ? nxt : cur;
        lds_h[row + ua] = __float2half(uv);
    }
    __syncthreads();

    // ---- 4. writeback: f16 LDS -> f32 global, NON-TEMPORAL float4 stores ----
    floatx4* __restrict__ out4 = reinterpret_cast<floatx4*>(out + blockBase);
    #pragma unroll
    for (int i = 0; i < VEC_ITERS; ++i) {
        const int idx = i * TPB + t;
        const uint2 u = *reinterpret_cast<const uint2*>(&lds_h[4 * idx]);
        const __half2 lo = *reinterpret_cast<const __half2*>(&u.x);
        const __half2 hi = *reinterpret_cast<const __half2*>(&u.y);
        floatx4 v;
        v.x = __half2float(__low2half(lo));
        v.y = __half2float(__high2half(lo));
        v.z = __half2float(__low2half(hi));
        v.w = __half2float(__high2half(hi));
        __builtin_nontemporal_store(v, &out4[idx]);
    }
    #pragma unroll
    for (int i = 0; i < TAIL_ITERS; ++i) {
        const int f = VEC_FLOATS + i * TPB + t;
        __builtin_nontemporal_store(__half2float(lds_h[f]), &out[blockBase + f]);
    }
}

extern "C" void kernel_launch(void* const* d_in, const int* in_sizes, int n_in,
                              void* d_out, int out_size, void* d_ws, size_t ws_size,
                              hipStream_t stream) {
    const float* reward   = (const float*)d_in[0];
    const float* probs    = (const float*)d_in[1];
    const float* not_done = (const float*)d_in[2];
    float* out = (float*)d_out;

    const int bs = in_sizes[0];            // 524288
    const int blocks = bs / TPB;           // 2048

    hipLaunchKernelGGL(catproj_kernel, dim3(blocks), dim3(TPB), 0, stream,
                       reward, probs, not_done, out);
}